// Round 2
// baseline (296.693 us; speedup 1.0000x reference)
//
#include <hip/hip_runtime.h>
#include <math.h>

#define BB 128
#define CIN 512
#define HW 64
#define OUTC 256
#define EMB 4096
#define DDIM 4096
#define ES 32
#define QCH 32          // D-chunks in k_main (128 d each)

// workspace layout (float offsets) — ft no longer materialized
#define ENC_OFF   0          // 8192 ints
#define TSUM_OFF  8192       // 4096
#define TLOGT_OFF 12288      // 4096
#define PL_OFF    16384      // 128*32*64 = 262144
#define PD_OFF    278528     // 4096

typedef short short8 __attribute__((ext_vector_type(8)));
typedef float floatx4 __attribute__((ext_vector_type(4)));

__device__ __forceinline__ unsigned short f2bf(float f) {
    unsigned int u = __builtin_bit_cast(unsigned int, f);
    u += 0x7FFFu + ((u >> 16) & 1u);          // RNE; inputs are finite
    return (unsigned short)(u >> 16);
}

// ---------------- K1: fused LDA GEMM + subclass argmin, one block per b ----
// GEMM: 64px x 256out x 512k via bf16 MFMA, 4 waves each own a 64-out slice.
// Output stays in LDS (ftb, pad-65), never touches HBM. Class centers are
// async-staged (global_load_lds) under the GEMM. Then 4 waves x 8 centers
// argmin over the LDS tile -> enc.
__global__ __launch_bounds__(256) void k_front(const float* __restrict__ feat,
                                               const float* __restrict__ w,
                                               const float* __restrict__ bias,
                                               const float* __restrict__ cent,
                                               const int* __restrict__ labels,
                                               int* __restrict__ enc,
                                               float* __restrict__ out) {
    __shared__ unsigned short As[64 * 40];            // A staging, stride 40
    __shared__ float ftb[OUTC * 65];                  // [o][p], pad 65
    __shared__ __align__(16) float cbuf[ES * OUTC];   // 32 KB centers
    __shared__ float vred[256];
    __shared__ int   ired[256];
    int b = blockIdx.x;
    int tid = threadIdx.x;
    if (b == 0 && tid == 0) *out = 0.f;               // zero loss accumulator
    int lane = tid & 63, wid = tid >> 6;
    int cls = labels[b];
    // async-stage the class's 32x256 centers; first __syncthreads drains vmcnt
    const float* cbase = cent + (size_t)cls * ES * OUTC;
#pragma unroll
    for (int it = 0; it < 8; ++it) {
        int ch = wid * 8 + it;
        __builtin_amdgcn_global_load_lds(
            (const __attribute__((address_space(1))) void*)(cbase + ch * OUTC + lane * 4),
            (__attribute__((address_space(3))) void*)&cbuf[ch * OUTC],
            16, 0, 0);
    }
    int m = lane & 15, q = lane >> 4;
    int ccs = tid >> 4;                       // staging: channels ccs, ccs+16
    int p4 = (tid & 15) * 4;                  // staging: 4 consecutive pixels
    const float* fbase = feat + (size_t)b * CIN * HW;
    const float* wr0 = w + (size_t)(wid * 64 +  0 + m) * CIN;
    const float* wr1 = w + (size_t)(wid * 64 + 16 + m) * CIN;
    const float* wr2 = w + (size_t)(wid * 64 + 32 + m) * CIN;
    const float* wr3 = w + (size_t)(wid * 64 + 48 + m) * CIN;
    floatx4 acc[4][4] = {};
    for (int kt = 0; kt < 16; ++kt) {
        int k0 = kt * 32;
        float4 v0 = *(const float4*)(fbase + (size_t)(k0 + ccs) * HW + p4);
        float4 v1 = *(const float4*)(fbase + (size_t)(k0 + ccs + 16) * HW + p4);
        const float* wrs[4] = {wr0, wr1, wr2, wr3};
        short8 bfn[4];
#pragma unroll
        for (int nf = 0; nf < 4; ++nf) {
            float4 w0 = *(const float4*)(wrs[nf] + k0 + 4 * q);
            float4 w1 = *(const float4*)(wrs[nf] + k0 + 16 + 4 * q);
            short8 bf;
            bf[0] = (short)f2bf(w0.x); bf[1] = (short)f2bf(w1.x);
            bf[2] = (short)f2bf(w0.y); bf[3] = (short)f2bf(w1.y);
            bf[4] = (short)f2bf(w0.z); bf[5] = (short)f2bf(w1.z);
            bf[6] = (short)f2bf(w0.w); bf[7] = (short)f2bf(w1.w);
            bfn[nf] = bf;
        }
        ushort2 pk;
        pk.x = f2bf(v0.x); pk.y = f2bf(v1.x);
        *(ushort2*)&As[(p4 + 0) * 40 + 2 * ccs] = pk;
        pk.x = f2bf(v0.y); pk.y = f2bf(v1.y);
        *(ushort2*)&As[(p4 + 1) * 40 + 2 * ccs] = pk;
        pk.x = f2bf(v0.z); pk.y = f2bf(v1.z);
        *(ushort2*)&As[(p4 + 2) * 40 + 2 * ccs] = pk;
        pk.x = f2bf(v0.w); pk.y = f2bf(v1.w);
        *(ushort2*)&As[(p4 + 3) * 40 + 2 * ccs] = pk;
        __syncthreads();
#pragma unroll
        for (int mt = 0; mt < 4; ++mt) {
            short8 af = *(short8*)&As[(mt * 16 + m) * 40 + q * 8];
#pragma unroll
            for (int nf = 0; nf < 4; ++nf)
                acc[mt][nf] = __builtin_amdgcn_mfma_f32_16x16x32_bf16(af, bfn[nf], acc[mt][nf], 0, 0, 0);
        }
        __syncthreads();
    }
    float bvs[4];
#pragma unroll
    for (int nf = 0; nf < 4; ++nf) bvs[nf] = bias[wid * 64 + nf * 16 + m];
#pragma unroll
    for (int mt = 0; mt < 4; ++mt)
#pragma unroll
        for (int nf = 0; nf < 4; ++nf)
#pragma unroll
            for (int r = 0; r < 4; ++r)
                ftb[(wid * 64 + nf * 16 + m) * 65 + mt * 16 + q * 4 + r] =
                    acc[mt][nf][r] + bvs[nf];
    __syncthreads();
    // ---- argmin over 32 in-class centers; wave jg owns centers jg*8..+7
    int p = tid & 63, jg = tid >> 6;
    float sc[8];
#pragma unroll
    for (int jj = 0; jj < 8; ++jj) sc[jj] = 0.f;
    for (int o = 0; o < OUTC; o += 4) {
        float x0 = ftb[(o + 0) * 65 + p];     // banks (o+p)%32: 2-way, free
        float x1 = ftb[(o + 1) * 65 + p];
        float x2 = ftb[(o + 2) * 65 + p];
        float x3 = ftb[(o + 3) * 65 + p];
        float m0 = -2.f * x0, m1 = -2.f * x1, m2 = -2.f * x2, m3 = -2.f * x3;
#pragma unroll
        for (int jj = 0; jj < 8; ++jj) {
            float4 c4 = *(const float4*)&cbuf[(jg * 8 + jj) * OUTC + o];  // uniform: broadcast
            float s = sc[jj];
            s = fmaf(c4.x, c4.x + m0, s);
            s = fmaf(c4.y, c4.y + m1, s);
            s = fmaf(c4.z, c4.z + m2, s);
            s = fmaf(c4.w, c4.w + m3, s);
            sc[jj] = s;
        }
    }
    float best = sc[0]; int bj = jg * 8;
#pragma unroll
    for (int jj = 1; jj < 8; ++jj)
        if (sc[jj] < best) { best = sc[jj]; bj = jg * 8 + jj; }
    vred[jg * 64 + p] = best;
    ired[jg * 64 + p] = bj;
    __syncthreads();
    if (tid < 64) {
        float bv = vred[tid]; int bi = ired[tid];
#pragma unroll
        for (int g = 1; g < 4; ++g) {
            float v = vred[g * 64 + tid];
            if (v < bv) { bv = v; bi = ired[g * 64 + tid]; }
        }
        enc[b * 64 + tid] = cls * ES + bi;
    }
}

// ---------------- K2: main stream (blocks 0..4095)  ||  rowsum (4096..8191) -
// main: per-(b,q) per-pixel sumexp + block-scalar dot (Sum_p D[p] identity).
// rowsum: per-row sums of teacher_scores (present classes only) — independent,
// fused into this grid so its 42 MB stream overlaps the 134 MB scores stream.
__global__ __launch_bounds__(256) void k_main(const float* __restrict__ scores,
                                              const float* __restrict__ ts,
                                              const int* __restrict__ enc,
                                              const int* __restrict__ labels,
                                              float* __restrict__ pl,
                                              float* __restrict__ pd,
                                              float* __restrict__ tsum,
                                              float* __restrict__ tlogt) {
    __shared__ float st[128 * 65];            // [d][p], pad 65
    __shared__ float redl[4 * 64];
    __shared__ int   etab[64];
    __shared__ float rd[4];
    __shared__ int present;
    __shared__ float r8[8];
    int bx = blockIdx.x;
    int tid = threadIdx.x;
    if (bx >= BB * QCH) {
        // ---------------- rowsum role ----------------
        int e = bx - BB * QCH;
        if (tid == 0) present = 0;
        __syncthreads();
        int cls = e >> 5;
        if (tid < BB && labels[tid] == cls) present = 1;
        __syncthreads();
        if (!present) return;
        const float* row = ts + (size_t)e * DDIM;
        float st_ = 0.f, sl = 0.f;
#pragma unroll
        for (int i = 0; i < 4; ++i) {
            float4 t4 = *(const float4*)&row[tid * 4 + i * 1024];
            float tv[4] = {t4.x, t4.y, t4.z, t4.w};
#pragma unroll
            for (int j = 0; j < 4; ++j) {
                float t = tv[j];
                st_ += t;
                sl += (t > 0.f) ? t * logf(t) : 0.f;
            }
        }
        for (int off = 32; off; off >>= 1) {
            st_ += __shfl_down(st_, off);
            sl += __shfl_down(sl, off);
        }
        int lane = tid & 63, wv = tid >> 6;
        if (lane == 0) { r8[wv] = st_; r8[4 + wv] = sl; }
        __syncthreads();
        if (tid == 0) {
            tsum[e]  = r8[0] + r8[1] + r8[2] + r8[3];
            tlogt[e] = r8[4] + r8[5] + r8[6] + r8[7];
        }
        return;
    }
    // ---------------- main role ----------------
    int b = bx >> 5, q = bx & 31;
    int lane = tid & 63, wv = tid >> 6;
    int pg = lane & 15, lg = lane >> 4;
    if (tid < 64) etab[tid] = enc[b * 64 + tid] * DDIM;
    int p4 = pg * 4;
    int dl = wv * 4 + lg;                     // local d in [0,16), +16*it
    const float* sptr = scores + (size_t)b * DDIM * HW + (size_t)(q * 128 + dl) * HW + p4;
    float l0 = 0.f, l1 = 0.f, l2 = 0.f, l3 = 0.f;
#pragma unroll
    for (int it = 0; it < 8; ++it) {
        float4 s4 = *(const float4*)(sptr + (size_t)(it * 16) * HW);
        float* sw = &st[(dl + it * 16) * 65 + p4];    // banks (d+p)%32: free
        sw[0] = s4.x; sw[1] = s4.y; sw[2] = s4.z; sw[3] = s4.w;
        l0 += __expf(s4.x);
        l1 += __expf(s4.y);
        l2 += __expf(s4.z);
        l3 += __expf(s4.w);
    }
    l0 += __shfl_xor(l0, 16); l0 += __shfl_xor(l0, 32);
    l1 += __shfl_xor(l1, 16); l1 += __shfl_xor(l1, 32);
    l2 += __shfl_xor(l2, 16); l2 += __shfl_xor(l2, 32);
    l3 += __shfl_xor(l3, 16); l3 += __shfl_xor(l3, 32);
    if (lg == 0) {
        redl[wv * 64 + p4 + 0] = l0;
        redl[wv * 64 + p4 + 1] = l1;
        redl[wv * 64 + p4 + 2] = l2;
        redl[wv * 64 + p4 + 3] = l3;
    }
    __syncthreads();
    if (tid < 64) {
        float L = redl[tid] + redl[64 + tid] + redl[128 + tid] + redl[192 + tid];
        pl[(b * QCH + q) * 64 + tid] = L;
    }
    // ---- phase 2: D_block = sum_{p,d in chunk} st[d][p] * ts[e_p][d]
    int d = tid & 127, ph2 = tid >> 7;        // 2 threads per d, split p-range
    const float* tsq = ts + (size_t)q * 128 + d;
    float D = 0.f;
#pragma unroll 8
    for (int i = 0; i < 32; ++i) {
        int p = ph2 * 32 + i;                 // wave-uniform p
        float sv = st[d * 65 + p];            // banks (d+p)%32: 2-way, free
        float tv = tsq[etab[p]];              // lanes span d: 256B coalesced
        D = fmaf(sv, tv, D);
    }
#pragma unroll
    for (int off = 1; off < 64; off <<= 1) D += __shfl_xor(D, off);
    if (lane == 0) rd[wv] = D;
    __syncthreads();
    if (tid == 0) pd[b * QCH + q] = rd[0] + rd[1] + rd[2] + rd[3];
}

// ---------------- K3: merge partials, final loss ----------------------------
__global__ __launch_bounds__(64) void k_final(const float* __restrict__ pl,
                                              const float* __restrict__ pd,
                                              const int* __restrict__ enc,
                                              const float* __restrict__ tsum,
                                              const float* __restrict__ tlogt,
                                              float* __restrict__ out) {
    int b = blockIdx.x, p = threadIdx.x;
    int base = b * QCH * 64 + p;
    float L = 0.f;
#pragma unroll
    for (int qq = 0; qq < QCH; ++qq) L += pl[base + qq * 64];
    float lse = logf(L);
    int e = enc[b * 64 + p];
    float row = tlogt[e] + tsum[e] * lse;
    if (p < QCH) row -= pd[b * QCH + p];      // sum_p of these = D_batch
    for (int off = 32; off; off >>= 1) row += __shfl_down(row, off);
    if (p == 0) atomicAdd(out, row * (1.f / 8192.f));
}

extern "C" void kernel_launch(void* const* d_in, const int* in_sizes, int n_in,
                              void* d_out, int out_size, void* d_ws, size_t ws_size,
                              hipStream_t stream) {
    const float* feat   = (const float*)d_in[0];
    const float* scores = (const float*)d_in[1];
    const int*   labels = (const int*)d_in[2];
    const float* ldaw   = (const float*)d_in[3];
    const float* ldab   = (const float*)d_in[4];
    const float* cent   = (const float*)d_in[5];
    const float* ts     = (const float*)d_in[6];
    float* out = (float*)d_out;
    float* ws  = (float*)d_ws;

    int*   enc   = (int*)(ws + ENC_OFF);
    float* tsum  = ws + TSUM_OFF;
    float* tlogt = ws + TLOGT_OFF;
    float* pl    = ws + PL_OFF;
    float* pd    = ws + PD_OFF;

    k_front<<<BB,            256, 0, stream>>>(feat, ldaw, ldab, cent, labels, enc, out);
    k_main <<<BB * QCH + EMB, 256, 0, stream>>>(scores, ts, enc, labels, pl, pd, tsum, tlogt);
    k_final<<<BB,             64, 0, stream>>>(pl, pd, enc, tsum, tlogt, out);
}